// Round 12
// baseline (302.957 us; speedup 1.0000x reference)
//
#include <hip/hip_runtime.h>

typedef __attribute__((ext_vector_type(8))) int i32x8;
typedef __attribute__((ext_vector_type(16))) float f32x16;
typedef unsigned short u16;
typedef unsigned int u32;
typedef unsigned char u8;

#define NN 1024
#define ETOT 523776
#define EPSV 1e-5f

// LDS layout (bytes)
#define L_PSUM 0      /* [64][4] f32 */
#define L_PSQ  1024
#define L_B1   2048   /* f32[512]; reused for epi partials after B2 */
#define L_G    4096
#define L_BB   5120
#define L_W3   6144
#define L_TILE 7168   /* 32 KiB: h1 fp8 [kq8][kh2][sub4][e64][8B]; A1 (16K) aliased at +16384 */
#define L_TOTAL 39936 /* x4 blocks = 159744 <= 163840 */

// scales: A1 x4, W1 x64 (G1 acc /256); h1 x16, W2g x64 (G2 acc /1024)
#define INV_G1 0.00390625f
#define INV_G2 0.0009765625f
#define SCL1 0x7F7F7F7F   /* e8m0 = 2^0 in every byte */

__device__ __forceinline__ u32 pk4fp8(float a, float b, float c, float d) {
  int p = __builtin_amdgcn_cvt_pk_fp8_f32(a, b, 0, false);
  p = __builtin_amdgcn_cvt_pk_fp8_f32(c, d, p, true);
  return (u32)p;
}

__device__ __forceinline__ i32x8 ldg32(const u8* p) {   // 32B global, 16B aligned
  uint4 lo = *(const uint4*)p;
  uint4 hi = *(const uint4*)(p + 16);
  i32x8 r;
  r[0]=(int)lo.x; r[1]=(int)lo.y; r[2]=(int)lo.z; r[3]=(int)lo.w;
  r[4]=(int)hi.x; r[5]=(int)hi.y; r[6]=(int)hi.z; r[7]=(int)hi.w;
  return r;
}
__device__ __forceinline__ i32x8 lds32(const char* base, int e8) {  // 4 x b64 subs
  uint2 s0 = *(const uint2*)(base + e8);
  uint2 s1 = *(const uint2*)(base + 512 + e8);
  uint2 s2 = *(const uint2*)(base + 1024 + e8);
  uint2 s3 = *(const uint2*)(base + 1536 + e8);
  i32x8 r;
  r[0]=(int)s0.x; r[1]=(int)s0.y; r[2]=(int)s1.x; r[3]=(int)s1.y;
  r[4]=(int)s2.x; r[5]=(int)s2.y; r[6]=(int)s3.x; r[7]=(int)s3.y;
  return r;
}

#define MFMA64(A,B,C) __builtin_amdgcn_mfma_scale_f32_32x32x64_f8f6f4((A),(B),(C),0,0,0,SCL1,0,SCL1)

// ---- prep: W1 -> [cb16][kq4][kh2][c32][32B] fp8 x64 ; W2*gamma -> [ob8][kq8][kh2][o32][32B] fp8 x64 ----
__global__ void prep_w(const float* __restrict__ W1, const float* __restrict__ W2,
                       const float* __restrict__ gammav,
                       u8* __restrict__ W1f, u8* __restrict__ W2f) {
  int idx = blockIdx.x*256 + threadIdx.x;        // [0, 131072)
  { int c = idx >> 8, k = idx & 255;
    float v = W1[k*512 + c] * 64.f;
    int p = __builtin_amdgcn_cvt_pk_fp8_f32(v, 0.f, 0, false);
    W1f[(c>>5)*8192 + (k>>6)*2048 + ((k>>5)&1)*1024 + (c&31)*32 + (k&31)] = (u8)(p & 0xff); }
  { int o = idx >> 9, c = idx & 511;
    float v = gammav[c] * W2[c*256 + o] * 64.f;
    int p = __builtin_amdgcn_cvt_pk_fp8_f32(v, 0.f, 0, false);
    W2f[(o>>5)*16384 + (c>>6)*2048 + ((c>>5)&1)*1024 + (o&31)*32 + (c&31)] = (u8)(p & 0xff); }
}

// ---- prep: G[o] = sum_c gamma[c]*W2[c,o]; BB[o] = b2[o] + sum_c beta[c]*W2[c,o] ----
__global__ void prep_vec(const float* __restrict__ W2, const float* __restrict__ gammav,
                         const float* __restrict__ betav, const float* __restrict__ b2v,
                         float* __restrict__ Gv, float* __restrict__ BBv) {
  int o = blockIdx.x, t = threadIdx.x;
  float g = 0.f, bb = 0.f;
  for (int c = t; c < 512; c += 64) {
    float w = W2[c*256 + o];
    g  += gammav[c] * w;
    bb += betav[c]  * w;
  }
  #pragma unroll
  for (int off = 1; off < 64; off <<= 1) {
    g  += __shfl_xor(g,  off, 64);
    bb += __shfl_xor(bb, off, 64);
  }
  if (t == 0) { Gv[o] = g; BBv[o] = bb + b2v[o]; }
}

// ---- main: 4-wave block = 8x8 node tile = 64 edges; swapped GEMMs, MX K=64 fp8 ----
__launch_bounds__(256, 4)
__global__ void edge_main(const float* __restrict__ emb,
                          const float* __restrict__ b1v,
                          const float* __restrict__ b3v,
                          const float* __restrict__ w3v,
                          const float* __restrict__ Gv,
                          const float* __restrict__ BBv,
                          const u8* __restrict__ W1f,
                          const u8* __restrict__ W2f,
                          float* __restrict__ out) {
  extern __shared__ char smem[];
  float* psum = (float*)(smem + L_PSUM);
  float* psq  = (float*)(smem + L_PSQ);
  float* sb1  = (float*)(smem + L_B1);           // b1, later epi partials
  float* sG   = (float*)(smem + L_G);
  float* sBB  = (float*)(smem + L_BB);
  float* sw3  = (float*)(smem + L_W3);
  char*  tile = smem + L_TILE;                   // h1: [kq8][kh2][sub4][e64][8B]
  char*  A1   = tile + 16384;                    // A1: [kq4][kh2][sub4][e64][8B] (aliased)

  const int tid  = threadIdx.x;
  const int w    = tid >> 6;
  const int lane = tid & 63;
  const int l31  = lane & 31;
  const int hi   = lane >> 5;

  // exact upper-triangle tile mapping: 8256 blocks
  int kblk = blockIdx.x;
  int bi = (int)((257.0f - sqrtf(66049.0f - 8.0f*(float)kblk)) * 0.5f);
  bi = bi < 0 ? 0 : (bi > 127 ? 127 : bi);
  while (bi*128 - bi*(bi-1)/2 > kblk) --bi;
  while ((bi+1)*128 - (bi+1)*bi/2 <= kblk) ++bi;
  const int bj = bi + (kblk - (bi*128 - bi*(bi-1)/2));
  const int i0 = bi*8, j0 = bj*8;

  // ---- stage A1 fp8 (x4): wave w stages k-chunk kq=w (64 k) for all 64 edges ----
  {
    const int e  = lane;
    const int sa = e >> 3, sb = e & 7;
    const int fbase = (w < 2) ? w*64 : (w - 2)*64;
    const float4* pei = (const float4*)(emb + (i0 + sa)*128 + fbase);
    const float4* pej = (const float4*)(emb + (j0 + sb)*128 + fbase);
    char* abase = A1 + w*4096 + e*8;
    #pragma unroll
    for (int g = 0; g < 8; ++g) {                // g = kh*4 + sub
      float4 x0 = pei[g*2], x1 = pei[g*2+1];
      float4 y0 = pej[g*2], y1 = pej[g*2+1];
      uint2 pk;
      if (w < 2) {
        pk.x = pk4fp8((x0.x-y0.x)*4.f, (x0.y-y0.y)*4.f, (x0.z-y0.z)*4.f, (x0.w-y0.w)*4.f);
        pk.y = pk4fp8((x1.x-y1.x)*4.f, (x1.y-y1.y)*4.f, (x1.z-y1.z)*4.f, (x1.w-y1.w)*4.f);
      } else {
        pk.x = pk4fp8((x0.x*y0.x)*4.f, (x0.y*y0.y)*4.f, (x0.z*y0.z)*4.f, (x0.w*y0.w)*4.f);
        pk.y = pk4fp8((x1.x*y1.x)*4.f, (x1.y*y1.y)*4.f, (x1.z*y1.z)*4.f, (x1.w*y1.w)*4.f);
      }
      *(uint2*)(abase + g*512) = pk;
    }
  }
  sb1[tid] = b1v[tid]; sb1[tid + 256] = b1v[tid + 256];
  sG[tid] = Gv[tid]; sBB[tid] = BBv[tid]; sw3[tid] = w3v[tid];
  __syncthreads();                               // B0

  f32x16 z16;
  #pragma unroll
  for (int i = 0; i < 16; ++i) z16[i] = 0.f;

  float sum0 = 0.f, sq0 = 0.f, sum1 = 0.f, sq1 = 0.f;
  f32x16 A00, A01, A10, A11;

  const u8* w1base = W1f + hi*1024 + l31*32;

  // h1-pass: +b1 (descale), relu, stats, fp8(x16) -> h1 [kq][kh][sub][e][8B]
  auto h1pass = [&](int ch, const f32x16& F00, const f32x16& F01,
                    const f32x16& F10, const f32x16& F11) {
    const int kq = w + 4*ch;                     // h1 k-chunk = c>>6
    #pragma unroll
    for (int f = 0; f < 2; ++f) {
      const f32x16& E0 = f ? F10 : F00;
      const f32x16& E1 = f ? F11 : F01;
      #pragma unroll
      for (int a = 0; a < 4; ++a) {
        const int c0 = kq*64 + f*32 + a*8 + hi*4;
        const float b0 = sb1[c0+0], b1_ = sb1[c0+1], b2_ = sb1[c0+2], b3_ = sb1[c0+3];
        char* dst = tile + kq*4096 + f*2048 + a*512 + hi*4;
        {
          float v0 = fmaxf(fmaf(F00[0]*0.f + E0[a*4+0], INV_G1, b0), 0.f);
          float v1 = fmaxf(fmaf(E0[a*4+1], INV_G1, b1_), 0.f);
          float v2 = fmaxf(fmaf(E0[a*4+2], INV_G1, b2_), 0.f);
          float v3 = fmaxf(fmaf(E0[a*4+3], INV_G1, b3_), 0.f);
          *(u32*)(dst + l31*8) = pk4fp8(v0*16.f, v1*16.f, v2*16.f, v3*16.f);
          sum0 += (v0+v1)+(v2+v3);
          sq0 = fmaf(v0,v0,sq0); sq0 = fmaf(v1,v1,sq0);
          sq0 = fmaf(v2,v2,sq0); sq0 = fmaf(v3,v3,sq0);
        }
        {
          float v0 = fmaxf(fmaf(E1[a*4+0], INV_G1, b0), 0.f);
          float v1 = fmaxf(fmaf(E1[a*4+1], INV_G1, b1_), 0.f);
          float v2 = fmaxf(fmaf(E1[a*4+2], INV_G1, b2_), 0.f);
          float v3 = fmaxf(fmaf(E1[a*4+3], INV_G1, b3_), 0.f);
          *(u32*)(dst + (l31+32)*8) = pk4fp8(v0*16.f, v1*16.f, v2*16.f, v3*16.f);
          sum1 += (v0+v1)+(v2+v3);
          sq1 = fmaf(v0,v0,sq1); sq1 = fmaf(v1,v1,sq1);
          sq1 = fmaf(v2,v2,sq1); sq1 = fmaf(v3,v3,sq1);
        }
      }
    }
  };

  // ---- G1 chalf 0: c-chunk kq = w (64 c), K=256 = 4 MX instrs per acc ----
  A00 = z16; A01 = z16; A10 = z16; A11 = z16;
  #pragma unroll
  for (int kq = 0; kq < 4; ++kq) {
    i32x8 af0 = ldg32(w1base + w*16384 + kq*2048);
    i32x8 af1 = ldg32(w1base + w*16384 + 8192 + kq*2048);
    const char* bb = A1 + kq*4096 + hi*2048;
    i32x8 bf0 = lds32(bb, l31*8);
    i32x8 bf1 = lds32(bb, (l31+32)*8);
    A00 = MFMA64(af0, bf0, A00);
    A01 = MFMA64(af0, bf1, A01);
    A10 = MFMA64(af1, bf0, A10);
    A11 = MFMA64(af1, bf1, A11);
  }
  h1pass(0, A00, A01, A10, A11);                 // writes kq=w (<16K): no A1 overlap

  // ---- G1 chalf 1: c-chunk kq = w+4 ----
  A00 = z16; A01 = z16; A10 = z16; A11 = z16;
  #pragma unroll
  for (int kq = 0; kq < 4; ++kq) {
    i32x8 af0 = ldg32(w1base + (w+4)*16384 + kq*2048);
    i32x8 af1 = ldg32(w1base + (w+4)*16384 + 8192 + kq*2048);
    const char* bb = A1 + kq*4096 + hi*2048;
    i32x8 bf0 = lds32(bb, l31*8);
    i32x8 bf1 = lds32(bb, (l31+32)*8);
    A00 = MFMA64(af0, bf0, A00);
    A01 = MFMA64(af0, bf1, A01);
    A10 = MFMA64(af1, bf0, A10);
    A11 = MFMA64(af1, bf1, A11);
  }
  __syncthreads();                               // B1: all A1 reads done
  h1pass(1, A00, A01, A10, A11);                 // writes kq=w+4 (over A1)

  // per-wave LN partials
  sum0 += __shfl_xor(sum0, 32, 64);  sq0 += __shfl_xor(sq0, 32, 64);
  sum1 += __shfl_xor(sum1, 32, 64);  sq1 += __shfl_xor(sq1, 32, 64);
  if (hi == 0) {
    psum[l31*4 + w] = sum0;       psq[l31*4 + w] = sq0;
    psum[(l31+32)*4 + w] = sum1;  psq[(l31+32)*4 + w] = sq1;
  }
  __syncthreads();                               // B2: h1 + partials visible

  // ---- in-lane stats for this lane's two edges ----
  float sc2A, smA, sc2B, smB;
  {
    float4 s = *(const float4*)(psum + l31*4);
    float4 q = *(const float4*)(psq  + l31*4);
    float su = (s.x+s.y)+(s.z+s.w), qu = (q.x+q.y)+(q.z+q.w);
    float mu = su * (1.f/512.f);
    float sc = rsqrtf(qu * (1.f/512.f) - mu*mu + EPSV);
    sc2A = sc * INV_G2; smA = mu * sc;
    s = *(const float4*)(psum + (l31+32)*4);
    q = *(const float4*)(psq  + (l31+32)*4);
    su = (s.x+s.y)+(s.z+s.w); qu = (q.x+q.y)+(q.z+q.w);
    mu = su * (1.f/512.f);
    sc = rsqrtf(qu * (1.f/512.f) - mu*mu + EPSV);
    sc2B = sc * INV_G2; smB = mu * sc;
  }

  // ---- G2: out2^T[o][e], wave owns o in [w*64, w*64+64); K=512 = 8 MX instrs ----
  f32x16 C00 = z16, C01 = z16, C10 = z16, C11 = z16;
  {
    const u8* w2base = W2f + (2*w)*16384 + hi*1024 + l31*32;
    #pragma unroll
    for (int kq = 0; kq < 8; ++kq) {
      i32x8 a0 = ldg32(w2base + kq*2048);
      i32x8 a1 = ldg32(w2base + 16384 + kq*2048);
      const char* bb = tile + kq*4096 + hi*2048;
      i32x8 b0 = lds32(bb, l31*8);
      i32x8 b1 = lds32(bb, (l31+32)*8);
      C00 = MFMA64(a0, b0, C00);
      C01 = MFMA64(a0, b1, C01);
      C10 = MFMA64(a1, b0, C10);
      C11 = MFMA64(a1, b1, C11);
    }
  }

  // ---- epilogue: LN-affine + relu + W3 dot (in-lane), partials -> sb1 region ----
  {
    float p0 = 0.f, p1 = 0.f;
    #pragma unroll
    for (int g = 0; g < 2; ++g) {
      const f32x16& E0 = g ? C10 : C00;
      const f32x16& E1 = g ? C11 : C01;
      #pragma unroll
      for (int rg = 0; rg < 16; ++rg) {
        const int o = w*64 + g*32 + (rg&3) + 8*(rg>>2) + 4*hi;
        const float gv = sG[o], bb = sBB[o], w3 = sw3[o];
        float t0 = fmaxf(fmaf(sc2A, E0[rg], fmaf(-smA, gv, bb)), 0.f);
        p0 = fmaf(t0, w3, p0);
        float t1 = fmaxf(fmaf(sc2B, E1[rg], fmaf(-smB, gv, bb)), 0.f);
        p1 = fmaf(t1, w3, p1);
      }
    }
    p0 += __shfl_xor(p0, 32, 64);
    p1 += __shfl_xor(p1, 32, 64);
    if (hi == 0) {                               // sb1: all b1 reads happened pre-B2
      sb1[l31*4 + w] = p0;
      sb1[(l31+32)*4 + w] = p1;
    }
  }
  __syncthreads();                               // B3

  // ---- flush logits + pairs ----
  if (tid < 64) {
    float4 s = *(const float4*)(sb1 + tid*4);
    float logit = (s.x+s.y)+(s.z+s.w) + b3v[0];
    int a = tid >> 3, b = tid & 7;
    int i = i0 + a, j = j0 + b;
    if (i < j) {
      int e = i*(2*NN - i - 1)/2 + (j - i - 1);
      out[e] = logit;
      out[ETOT + 2*e]     = (float)i;
      out[ETOT + 2*e + 1] = (float)j;
    }
  }
}

extern "C" void kernel_launch(void* const* d_in, const int* in_sizes, int n_in,
                              void* d_out, int out_size, void* d_ws, size_t ws_size,
                              hipStream_t stream) {
  const float* emb   = (const float*)d_in[0];
  const float* W1    = (const float*)d_in[1];
  const float* b1    = (const float*)d_in[2];
  const float* gamma = (const float*)d_in[3];
  const float* beta  = (const float*)d_in[4];
  const float* W2    = (const float*)d_in[5];
  const float* b2    = (const float*)d_in[6];
  const float* W3    = (const float*)d_in[7];
  const float* b3    = (const float*)d_in[8];

  char* ws   = (char*)d_ws;
  u8*  W1f = (u8*)ws;                            // 128 KiB
  u8*  W2f = (u8*)(ws + 131072);                 // 128 KiB
  float* Gv  = (float*)(ws + 262144);            // 1 KiB
  float* BBv = (float*)(ws + 263168);            // 1 KiB

  (void)hipFuncSetAttribute((const void*)edge_main,
                            hipFuncAttributeMaxDynamicSharedMemorySize, L_TOTAL);

  prep_w<<<512, 256, 0, stream>>>(W1, W2, gamma, W1f, W2f);
  prep_vec<<<256, 64, 0, stream>>>(W2, gamma, beta, b2, Gv, BBv);
  edge_main<<<8256, 256, L_TOTAL, stream>>>(emb, b1, b3, W3, Gv, BBv,
                                            W1f, W2f, (float*)d_out);
}

// Round 13
// 204.435 us; speedup vs baseline: 1.4819x; 1.4819x over previous
//
#include <hip/hip_runtime.h>

typedef __attribute__((ext_vector_type(8))) int i32x8;
typedef __attribute__((ext_vector_type(16))) float f32x16;
typedef unsigned int u32;
typedef unsigned char u8;

#define NN 1024
#define ETOT 523776
#define EPSV 1e-5f

// LDS layout (bytes)
#define L_PSUM 0      /* [64][12] f32 = 3072 (cols 0..7 used, pad) */
#define L_PSQ  3072   /* 3072 */
#define L_B1   6144   /* f32[512] = b1*16; reused for epi partials [64][8] after B2 */
#define L_G    8192   /* 1024 */
#define L_BB   9216   /* 1024 */
#define L_W3   10240  /* 1024 */
#define L_TILE 11264  /* 32 KiB: h1 fp8 [kq8][kh2][sub4][e64][8B]; A1 at +16384 (aliased under h1 kq4..7) */
#define L_TOTAL 44032 /* 3 blocks/CU by LDS; VGPR is the real cap */

#define SCL1 0x7F7F7F7F   /* e8m0 = 2^0 in every byte */

__device__ __forceinline__ u32 pk4fp8(float a, float b, float c, float d) {
  int p = __builtin_amdgcn_cvt_pk_fp8_f32(a, b, 0, false);
  p = __builtin_amdgcn_cvt_pk_fp8_f32(c, d, p, true);
  return (u32)p;
}
__device__ __forceinline__ i32x8 ldg32(const u8* p) {
  uint4 lo = *(const uint4*)p;
  uint4 hi = *(const uint4*)(p + 16);
  i32x8 r;
  r[0]=(int)lo.x; r[1]=(int)lo.y; r[2]=(int)lo.z; r[3]=(int)lo.w;
  r[4]=(int)hi.x; r[5]=(int)hi.y; r[6]=(int)hi.z; r[7]=(int)hi.w;
  return r;
}
__device__ __forceinline__ i32x8 lds32(const char* base, int e8) {
  uint2 s0 = *(const uint2*)(base + e8);
  uint2 s1 = *(const uint2*)(base + 512 + e8);
  uint2 s2 = *(const uint2*)(base + 1024 + e8);
  uint2 s3 = *(const uint2*)(base + 1536 + e8);
  i32x8 r;
  r[0]=(int)s0.x; r[1]=(int)s0.y; r[2]=(int)s1.x; r[3]=(int)s1.y;
  r[4]=(int)s2.x; r[5]=(int)s2.y; r[6]=(int)s3.x; r[7]=(int)s3.y;
  return r;
}
#define MFMA64(A,B,C) __builtin_amdgcn_mfma_scale_f32_32x32x64_f8f6f4((A),(B),(C),0,0,0,SCL1,0,SCL1)

// ---- prep: W1 -> [cb16][kq4][kh2][c32][32B] fp8 x64 ; W2*gamma -> [ob8][kq8][kh2][o32][32B] fp8 x64 ----
__global__ void prep_w(const float* __restrict__ W1, const float* __restrict__ W2,
                       const float* __restrict__ gammav,
                       u8* __restrict__ W1f, u8* __restrict__ W2f) {
  int idx = blockIdx.x*256 + threadIdx.x;
  { int c = idx >> 8, k = idx & 255;
    float v = W1[k*512 + c] * 64.f;
    int p = __builtin_amdgcn_cvt_pk_fp8_f32(v, 0.f, 0, false);
    W1f[(c>>5)*8192 + (k>>6)*2048 + ((k>>5)&1)*1024 + (c&31)*32 + (k&31)] = (u8)(p & 0xff); }
  { int o = idx >> 9, c = idx & 511;
    float v = gammav[c] * W2[c*256 + o] * 64.f;
    int p = __builtin_amdgcn_cvt_pk_fp8_f32(v, 0.f, 0, false);
    W2f[(o>>5)*16384 + (c>>6)*2048 + ((c>>5)&1)*1024 + (o&31)*32 + (c&31)] = (u8)(p & 0xff); }
}

__global__ void prep_vec(const float* __restrict__ W2, const float* __restrict__ gammav,
                         const float* __restrict__ betav, const float* __restrict__ b2v,
                         float* __restrict__ Gv, float* __restrict__ BBv) {
  int o = blockIdx.x, t = threadIdx.x;
  float g = 0.f, bb = 0.f;
  for (int c = t; c < 512; c += 64) {
    float w = W2[c*256 + o];
    g  += gammav[c] * w;
    bb += betav[c]  * w;
  }
  #pragma unroll
  for (int off = 1; off < 64; off <<= 1) {
    g  += __shfl_xor(g,  off, 64);
    bb += __shfl_xor(bb, off, 64);
  }
  if (t == 0) { Gv[o] = g; BBv[o] = bb + b2v[o]; }
}

// ---- main: 8-wave (512-thr) block = 64 edges; swapped GEMMs, MX K=64 fp8, 2-acc waves ----
__launch_bounds__(512, 4)
__global__ void edge_main(const float* __restrict__ emb,
                          const float* __restrict__ b1v,
                          const float* __restrict__ b3v,
                          const float* __restrict__ w3v,
                          const float* __restrict__ Gv,
                          const float* __restrict__ BBv,
                          const u8* __restrict__ W1f,
                          const u8* __restrict__ W2f,
                          float* __restrict__ out) {
  extern __shared__ char smem[];
  float* psum = (float*)(smem + L_PSUM);         // [64][12]
  float* psq  = (float*)(smem + L_PSQ);
  float* sb1  = (float*)(smem + L_B1);           // b1*16; later epi partials
  float* sG   = (float*)(smem + L_G);
  float* sBB  = (float*)(smem + L_BB);
  float* sw3  = (float*)(smem + L_W3);
  char*  tile = smem + L_TILE;                   // h1 [kq8][kh2][sub4][e64][8B]
  char*  A1   = tile + 16384;                    // A1 [kq4][kh2][sub4][e64][8B]

  const int tid  = threadIdx.x;
  const int w    = tid >> 6;                     // wave 0..7
  const int lane = tid & 63;
  const int l31  = lane & 31;
  const int hi   = lane >> 5;

  // exact upper-triangle tile mapping: 8256 blocks
  int kblk = blockIdx.x;
  int bi = (int)((257.0f - sqrtf(66049.0f - 8.0f*(float)kblk)) * 0.5f);
  bi = bi < 0 ? 0 : (bi > 127 ? 127 : bi);
  while (bi*128 - bi*(bi-1)/2 > kblk) --bi;
  while ((bi+1)*128 - (bi+1)*bi/2 <= kblk) ++bi;
  const int bj = bi + (kblk - (bi*128 - bi*(bi-1)/2));
  const int i0 = bi*8, j0 = bj*8;

  // ---- stage A1 fp8 (x4): wave w -> k-chunk [w*32, w*32+32) for all 64 edges ----
  {
    const int e  = lane;
    const int d0 = (w & 3) * 32;                 // feature base
    const float4* pei = (const float4*)(emb + (i0 + (e>>3))*128 + d0);
    const float4* pej = (const float4*)(emb + (j0 + (e&7))*128 + d0);
    char* base = A1 + (w>>1)*4096 + (w&1)*2048 + e*8;
    #pragma unroll
    for (int s = 0; s < 4; ++s) {                // sub = 8 k each
      float4 x0 = pei[s*2], x1 = pei[s*2+1];
      float4 y0 = pej[s*2], y1 = pej[s*2+1];
      uint2 pk;
      if (w < 4) {
        pk.x = pk4fp8((x0.x-y0.x)*4.f, (x0.y-y0.y)*4.f, (x0.z-y0.z)*4.f, (x0.w-y0.w)*4.f);
        pk.y = pk4fp8((x1.x-y1.x)*4.f, (x1.y-y1.y)*4.f, (x1.z-y1.z)*4.f, (x1.w-y1.w)*4.f);
      } else {
        pk.x = pk4fp8((x0.x*y0.x)*4.f, (x0.y*y0.y)*4.f, (x0.z*y0.z)*4.f, (x0.w*y0.w)*4.f);
        pk.y = pk4fp8((x1.x*y1.x)*4.f, (x1.y*y1.y)*4.f, (x1.z*y1.z)*4.f, (x1.w*y1.w)*4.f);
      }
      *(uint2*)(base + s*512) = pk;
    }
  }
  sb1[tid] = b1v[tid] * 16.f;                    // pre-scaled bias
  if (tid < 256) { sG[tid] = Gv[tid]; sBB[tid] = BBv[tid]; sw3[tid] = w3v[tid]; }
  __syncthreads();                               // B0

  f32x16 z16;
  #pragma unroll
  for (int i = 0; i < 16; ++i) z16[i] = 0.f;

  float sumS0 = 0.f, sqS0 = 0.f, sumS1 = 0.f, sqS1 = 0.f;
  f32x16 A0, A1acc;

  // h1-pass for c-chunk cb: lane holds 16 c x 2 edges; store = fmax(E/16 + 16*b1, 0)
  auto h1pass = [&](int cb, const f32x16& E0, const f32x16& E1) {
    char* dbase = tile + (cb>>1)*4096 + (cb&1)*2048 + hi*4;
    #pragma unroll
    for (int g = 0; g < 4; ++g) {
      const int c0 = cb*32 + g*8 + hi*4;
      const float b0 = sb1[c0+0], b1_ = sb1[c0+1], b2_ = sb1[c0+2], b3_ = sb1[c0+3];
      char* dst = dbase + g*512;
      {
        float v0 = fmaxf(fmaf(E0[g*4+0], 0.0625f, b0), 0.f);
        float v1 = fmaxf(fmaf(E0[g*4+1], 0.0625f, b1_), 0.f);
        float v2 = fmaxf(fmaf(E0[g*4+2], 0.0625f, b2_), 0.f);
        float v3 = fmaxf(fmaf(E0[g*4+3], 0.0625f, b3_), 0.f);
        *(u32*)(dst + l31*8) = pk4fp8(v0, v1, v2, v3);
        sumS0 += (v0+v1)+(v2+v3);
        sqS0 = fmaf(v0,v0,sqS0); sqS0 = fmaf(v1,v1,sqS0);
        sqS0 = fmaf(v2,v2,sqS0); sqS0 = fmaf(v3,v3,sqS0);
      }
      {
        float v0 = fmaxf(fmaf(E1[g*4+0], 0.0625f, b0), 0.f);
        float v1 = fmaxf(fmaf(E1[g*4+1], 0.0625f, b1_), 0.f);
        float v2 = fmaxf(fmaf(E1[g*4+2], 0.0625f, b2_), 0.f);
        float v3 = fmaxf(fmaf(E1[g*4+3], 0.0625f, b3_), 0.f);
        *(u32*)(dst + (l31+32)*8) = pk4fp8(v0, v1, v2, v3);
        sumS1 += (v0+v1)+(v2+v3);
        sqS1 = fmaf(v0,v0,sqS1); sqS1 = fmaf(v1,v1,sqS1);
        sqS1 = fmaf(v2,v2,sqS1); sqS1 = fmaf(v3,v3,sqS1);
      }
    }
  };

  const u8* w1base = W1f + hi*1024 + l31*32;

  // ---- G1 pass 0: cb = w ----
  A0 = z16; A1acc = z16;
  #pragma unroll
  for (int kq = 0; kq < 4; ++kq) {
    i32x8 af = ldg32(w1base + w*8192 + kq*2048);
    const char* bbp = A1 + kq*4096 + hi*2048;
    i32x8 bf0 = lds32(bbp, l31*8);
    i32x8 bf1 = lds32(bbp, (l31+32)*8);
    A0    = MFMA64(af, bf0, A0);
    A1acc = MFMA64(af, bf1, A1acc);
  }
  h1pass(w, A0, A1acc);                          // kq_h = w>>1 < 4: below A1, safe

  // ---- G1 pass 1: cb = w + 8 ----
  A0 = z16; A1acc = z16;
  #pragma unroll
  for (int kq = 0; kq < 4; ++kq) {
    i32x8 af = ldg32(w1base + (w+8)*8192 + kq*2048);
    const char* bbp = A1 + kq*4096 + hi*2048;
    i32x8 bf0 = lds32(bbp, l31*8);
    i32x8 bf1 = lds32(bbp, (l31+32)*8);
    A0    = MFMA64(af, bf0, A0);
    A1acc = MFMA64(af, bf1, A1acc);
  }
  __syncthreads();                               // B1: all A1 reads done
  h1pass(w + 8, A0, A1acc);                      // kq_h >= 4: overwrites A1 region

  // LN partials: combine hi halves, one slot per (edge, wave)
  sumS0 += __shfl_xor(sumS0, 32, 64);  sqS0 += __shfl_xor(sqS0, 32, 64);
  sumS1 += __shfl_xor(sumS1, 32, 64);  sqS1 += __shfl_xor(sqS1, 32, 64);
  if (hi == 0) {
    psum[l31*12 + w] = sumS0;       psq[l31*12 + w] = sqS0;
    psum[(l31+32)*12 + w] = sumS1;  psq[(l31+32)*12 + w] = sqS1;
  }
  __syncthreads();                               // B2: h1 + partials visible

  // ---- in-lane stats for this lane's two edges (sums are of 16*v) ----
  float sc2A, smA, sc2B, smB;
  {
    float4 s0 = *(const float4*)(psum + l31*12);
    float4 s1 = *(const float4*)(psum + l31*12 + 4);
    float4 q0 = *(const float4*)(psq  + l31*12);
    float4 q1 = *(const float4*)(psq  + l31*12 + 4);
    float su = ((s0.x+s0.y)+(s0.z+s0.w)) + ((s1.x+s1.y)+(s1.z+s1.w));
    float qu = ((q0.x+q0.y)+(q0.z+q0.w)) + ((q1.x+q1.y)+(q1.z+q1.w));
    float mu = su * (1.f/8192.f);
    float sc = rsqrtf(qu * (1.f/131072.f) - mu*mu + EPSV);
    sc2A = sc * (1.f/1024.f); smA = mu * sc;
    s0 = *(const float4*)(psum + (l31+32)*12);
    s1 = *(const float4*)(psum + (l31+32)*12 + 4);
    q0 = *(const float4*)(psq  + (l31+32)*12);
    q1 = *(const float4*)(psq  + (l31+32)*12 + 4);
    su = ((s0.x+s0.y)+(s0.z+s0.w)) + ((s1.x+s1.y)+(s1.z+s1.w));
    qu = ((q0.x+q0.y)+(q0.z+q0.w)) + ((q1.x+q1.y)+(q1.z+q1.w));
    mu = su * (1.f/8192.f);
    sc = rsqrtf(qu * (1.f/131072.f) - mu*mu + EPSV);
    sc2B = sc * (1.f/1024.f); smB = mu * sc;
  }

  // ---- G2: wave owns o-chunk w (32 o); K=512 = 8 MX instrs per acc ----
  f32x16 C0 = z16, C1 = z16;
  {
    const u8* w2base = W2f + w*16384 + hi*1024 + l31*32;
    #pragma unroll
    for (int kq = 0; kq < 8; ++kq) {
      i32x8 a = ldg32(w2base + kq*2048);
      const char* bbp = tile + kq*4096 + hi*2048;
      i32x8 b0 = lds32(bbp, l31*8);
      i32x8 b1 = lds32(bbp, (l31+32)*8);
      C0 = MFMA64(a, b0, C0);
      C1 = MFMA64(a, b1, C1);
    }
  }

  // ---- epilogue: LN-affine + relu + W3 dot (in-lane), partials -> sb1 region ----
  {
    float p0 = 0.f, p1 = 0.f;
    #pragma unroll
    for (int rg = 0; rg < 16; ++rg) {
      const int o = w*32 + (rg&3) + 8*(rg>>2) + 4*hi;
      const float gv = sG[o], bb = sBB[o], w3 = sw3[o];
      float t0 = fmaxf(fmaf(sc2A, C0[rg], fmaf(-smA, gv, bb)), 0.f);
      p0 = fmaf(t0, w3, p0);
      float t1 = fmaxf(fmaf(sc2B, C1[rg], fmaf(-smB, gv, bb)), 0.f);
      p1 = fmaf(t1, w3, p1);
    }
    p0 += __shfl_xor(p0, 32, 64);
    p1 += __shfl_xor(p1, 32, 64);
    if (hi == 0) {                               // sb1: b1 reads all pre-B2 -> safe
      sb1[l31*8 + w] = p0;
      sb1[(l31+32)*8 + w] = p1;
    }
  }
  __syncthreads();                               // B3

  // ---- flush logits + pairs ----
  if (tid < 64) {
    float4 s0 = *(const float4*)(sb1 + tid*8);
    float4 s1 = *(const float4*)(sb1 + tid*8 + 4);
    float logit = ((s0.x+s0.y)+(s0.z+s0.w)) + ((s1.x+s1.y)+(s1.z+s1.w)) + b3v[0];
    int a = tid >> 3, b = tid & 7;
    int i = i0 + a, j = j0 + b;
    if (i < j) {
      int e = i*(2*NN - i - 1)/2 + (j - i - 1);
      out[e] = logit;
      out[ETOT + 2*e]     = (float)i;
      out[ETOT + 2*e + 1] = (float)j;
    }
  }
}

extern "C" void kernel_launch(void* const* d_in, const int* in_sizes, int n_in,
                              void* d_out, int out_size, void* d_ws, size_t ws_size,
                              hipStream_t stream) {
  const float* emb   = (const float*)d_in[0];
  const float* W1    = (const float*)d_in[1];
  const float* b1    = (const float*)d_in[2];
  const float* gamma = (const float*)d_in[3];
  const float* beta  = (const float*)d_in[4];
  const float* W2    = (const float*)d_in[5];
  const float* b2    = (const float*)d_in[6];
  const float* W3    = (const float*)d_in[7];
  const float* b3    = (const float*)d_in[8];

  char* ws   = (char*)d_ws;
  u8*  W1f = (u8*)ws;                            // 128 KiB
  u8*  W2f = (u8*)(ws + 131072);                 // 128 KiB
  float* Gv  = (float*)(ws + 262144);            // 1 KiB
  float* BBv = (float*)(ws + 263168);            // 1 KiB

  (void)hipFuncSetAttribute((const void*)edge_main,
                            hipFuncAttributeMaxDynamicSharedMemorySize, L_TOTAL);

  prep_w<<<512, 256, 0, stream>>>(W1, W2, gamma, W1f, W2f);
  prep_vec<<<256, 64, 0, stream>>>(W2, gamma, beta, b2, Gv, BBv);
  edge_main<<<8256, 512, L_TOTAL, stream>>>(emb, b1, b3, W3, Gv, BBv,
                                            W1f, W2f, (float*)d_out);
}